// Round 5
// baseline (206.920 us; speedup 1.0000x reference)
//
#include <hip/hip_runtime.h>

#define DT 0.03f
#define SEQ_LEN 30
#define D_STEER (0.4f * 0.03f)

#define BT 64            // threads per block (one wave) == rows per block
#define PAD 31           // float4 stride per row in LDS (30 + 1 pad)

typedef float f32x2 __attribute__((ext_vector_type(2)));
typedef float f32x4 __attribute__((ext_vector_type(4)));

__global__ __launch_bounds__(64) void ccdec_kernel(
    const float* __restrict__ z,
    const float* __restrict__ init_state,
    float* __restrict__ out,
    int B)
{
    __shared__ f32x4 lds[BT * PAD];   // 31744 B -> 5 blocks/CU

    int tid = threadIdx.x;
    int b   = blockIdx.x * BT + tid;
    bool valid = (b < B);
    int bb = valid ? b : (B - 1);

    // ---- inputs (streaming, no reuse -> non-temporal) ----
    const f32x2* zp = reinterpret_cast<const f32x2*>(z) + (size_t)bb;
    f32x2 zv = __builtin_nontemporal_load(zp);
    const f32x2* stp = reinterpret_cast<const f32x2*>(init_state + 6ull * (size_t)bb);
    f32x2 s01 = __builtin_nontemporal_load(stp + 0);
    f32x2 s23 = __builtin_nontemporal_load(stp + 1);
    f32x2 s45 = __builtin_nontemporal_load(stp + 2);

    float x   = s01.x;
    float y   = s01.y;
    float psi = s23.x;
    float v   = s23.y;
    float last_st = s45.y;   // init_state[:,5]

    // ---- steering / pedal preamble (mirror clip_by_tensor semantics) ----
    float steering = zv.y * 0.5f;
    float tmin = last_st - D_STEER;
    float tmax = last_st + D_STEER;
    float r = (steering > tmin) ? steering : ((steering < tmin) ? tmin : 0.0f);
    r = (r <= tmax) ? r : tmax;
    steering = fminf(fmaxf(r, -0.5f), 0.5f);

    float pedal = zv.x * 2.5f;
    float beta  = fminf(fmaxf(steering, -0.5f), 0.5f);
    float a_t   = fminf(fmaxf(pedal, -2.5f), 2.5f);
    float tan_beta = __tanf(beta);
    float dpsi_k   = tan_beta * (1.0f / 2.5f) * DT;
    float adt      = a_t * DT;

    bool full_tile = ((blockIdx.x + 1) * BT <= B);

    if (full_tile) {
        // ---- compute all 30 steps into LDS (full rows) ----
        #pragma unroll
        for (int t = 0; t < SEQ_LEN; ++t) {
            float v1 = fminf(fmaxf(v + adt, 0.0f), 10.0f);
            psi = v * dpsi_k + psi;          // uses OLD v
            float s, c;
            __sincosf(psi, &s, &c);
            x = v1 * c * DT + x;
            y = v1 * s * DT + y;
            v = v1;
            f32x4 o; o.x = x; o.y = y; o.z = psi; o.w = v;
            lds[tid * PAD + t] = o;
        }
        __syncthreads();

        // ---- stream tile out flat: every wave store = 16 full aligned lines ----
        f32x4* outp4 = reinterpret_cast<f32x4*>(out) + (size_t)blockIdx.x * BT * SEQ_LEN;
        #pragma unroll
        for (int m = 0; m < SEQ_LEN; ++m) {
            int f  = tid + m * BT;           // 0 .. 1919, contiguous per wave
            int rr = f / SEQ_LEN;            // row within tile
            int jj = f - rr * SEQ_LEN;       // step
            __builtin_nontemporal_store(lds[rr * PAD + jj], outp4 + f);
        }
    } else {
        if (valid) {
            f32x4* outp = reinterpret_cast<f32x4*>(out + 120ull * (size_t)b);
            #pragma unroll
            for (int t = 0; t < SEQ_LEN; ++t) {
                float v1 = fminf(fmaxf(v + adt, 0.0f), 10.0f);
                psi = v * dpsi_k + psi;
                float s, c;
                __sincosf(psi, &s, &c);
                x = v1 * c * DT + x;
                y = v1 * s * DT + y;
                v = v1;
                f32x4 o; o.x = x; o.y = y; o.z = psi; o.w = v;
                outp[t] = o;
            }
        }
    }
}

extern "C" void kernel_launch(void* const* d_in, const int* in_sizes, int n_in,
                              void* d_out, int out_size, void* d_ws, size_t ws_size,
                              hipStream_t stream)
{
    const float* z          = (const float*)d_in[0];   // (B, 2) f32
    const float* init_state = (const float*)d_in[1];   // (B, 6) f32
    float* out = (float*)d_out;                        // (B, 30, 4) f32

    int B = in_sizes[0] / 2;
    int blocks = (B + BT - 1) / BT;
    ccdec_kernel<<<blocks, BT, 0, stream>>>(z, init_state, out, B);
}